// Round 7
// baseline (2116.452 us; speedup 1.0000x reference)
//
#include <hip/hip_runtime.h>

#define NB 8
#define NP 4096
#define NS 1024

typedef _Float16 f16x8 __attribute__((ext_vector_type(8)));
typedef _Float16 f16x4 __attribute__((ext_vector_type(4)));
typedef float f32x4 __attribute__((ext_vector_type(4)));

// DPP-fused max step: v = max(v, dpp_move(v, ctrl)). bound_ctrl=false keeps
// old value on invalid lanes -> max(v,v)=v, harmless.
#define DPP_MAX(v, ctrl)                                                     \
    v = fmaxf(v, __int_as_float(__builtin_amdgcn_update_dpp(                 \
                __float_as_int(v), __float_as_int(v), (ctrl), 0xf, 0xf, false)))

// ============================ FPS =============================
// One block per cloud, 256 threads (4 waves, 1/SIMD), 16 CONTIGUOUS points
// per thread (p = tid*16 + j): tie order (wave, lane, j) == ascending point
// index == the reference's first-index argmax.
// Inner loop is a bare 10-VALU chain (value only); winning coords recovered
// once by the winner lane (md[j]==mx select scan, exec-masked). ONE barrier
// per iteration (parity-double-buffered slots); every thread redundantly
// combines the 4 wave slots — measured faster than serialized combine +
// second barrier (r6 post-mortem). __launch_bounds__(256,1): 1 wave/SIMD,
// full VGPR budget, no spill (r4 post-mortem).
__global__ __launch_bounds__(256, 1) void fps_kernel(
        const float* __restrict__ pos,
        float* __restrict__ centers,
        float* __restrict__ out_pos,
        float* __restrict__ out_batch) {
#pragma clang fp contract(off)
    const int b = blockIdx.x;
    const int tid = threadIdx.x;
    const int lane = tid & 63;
    const int wid = tid >> 6;
    __shared__ float4 slot[2][4];   // [parity][wave]

    const float* pb = pos + (size_t)b * NP * 3;
    float px[16], py[16], pz[16], md[16];
    {
        const float4* pv = (const float4*)(pb + tid * 48);
        float4 q[12];
#pragma unroll
        for (int i = 0; i < 12; ++i) q[i] = pv[i];
#pragma unroll
        for (int j = 0; j < 4; ++j) {
            px[4 * j + 0] = q[3 * j].x;     py[4 * j + 0] = q[3 * j].y;     pz[4 * j + 0] = q[3 * j].z;
            px[4 * j + 1] = q[3 * j].w;     py[4 * j + 1] = q[3 * j + 1].x; pz[4 * j + 1] = q[3 * j + 1].y;
            px[4 * j + 2] = q[3 * j + 1].z; py[4 * j + 2] = q[3 * j + 1].w; pz[4 * j + 2] = q[3 * j + 2].x;
            px[4 * j + 3] = q[3 * j + 2].y; py[4 * j + 3] = q[3 * j + 2].z; pz[4 * j + 3] = q[3 * j + 2].w;
        }
    }
#pragma unroll
    for (int j = 0; j < 16; ++j) md[j] = __builtin_inff();
    for (int t = tid; t < NS; t += 256) out_batch[b * NS + t] = (float)b;

    float cx = pb[0], cy = pb[1], cz = pb[2];
    if (tid == 0) {
        size_t o = (size_t)(b * NS) * 3;
        centers[o + 0] = cx; centers[o + 1] = cy; centers[o + 2] = cz;
        out_pos[o + 0] = cx; out_pos[o + 1] = cy; out_pos[o + 2] = cz;
    }

    int par = 0;
    for (int t = 1; t < NS; ++t) {
        // ---- 10 VALU / point, two max accumulators for ILP ----
        float a0 = -1.0f, a1 = -1.0f;
#pragma unroll
        for (int j = 0; j < 16; ++j) {
            float dx = px[j] - cx; float sx = dx * dx;
            float dy = py[j] - cy; float sy = dy * dy;
            float dz = pz[j] - cz; float sz = dz * dz;
            float d = sx + sy; d = d + sz;
            float m = fminf(md[j], d);
            md[j] = m;
            if (j & 1) a1 = fmaxf(a1, m); else a0 = fmaxf(a0, m);
        }
        const float bv = fmaxf(a0, a1);
        // ---- wave max via DPP (valid in lane 63), SGPR broadcast ----
        float v = bv;
        DPP_MAX(v, 0x111);   // row_shr:1
        DPP_MAX(v, 0x112);   // row_shr:2
        DPP_MAX(v, 0x114);   // row_shr:4
        DPP_MAX(v, 0x118);   // row_shr:8
        DPP_MAX(v, 0x142);   // row_bcast:15
        DPP_MAX(v, 0x143);   // row_bcast:31
        const float mx = __int_as_float(
            __builtin_amdgcn_readlane(__float_as_int(v), 63));
        unsigned long long tie = __ballot(bv == mx);
        if (lane == __ffsll(tie) - 1) {      // lowest lane among ties
            // first j with md[j]==mx (descending scan -> earliest j wins)
            float wx = px[15], wy = py[15], wz = pz[15];
#pragma unroll
            for (int j = 14; j >= 0; --j) {
                bool e = (md[j] == mx);
                wx = e ? px[j] : wx;
                wy = e ? py[j] : wy;
                wz = e ? pz[j] : wz;
            }
            slot[par][wid] = make_float4(mx, wx, wy, wz);
        }
        __syncthreads();
        // ---- every thread combines the 4 slots (no 2nd barrier) ----
        float4 s0 = slot[par][0], s1 = slot[par][1];
        float4 s2 = slot[par][2], s3 = slot[par][3];
        float4 m01 = (s1.x > s0.x) ? s1 : s0;   // ties keep lower wave
        float4 m23 = (s3.x > s2.x) ? s3 : s2;
        float4 wn = (m23.x > m01.x) ? m23 : m01;
        cx = wn.y; cy = wn.z; cz = wn.w;
        if (tid == 0) {
            size_t o = (size_t)(b * NS + t) * 3;
            centers[o + 0] = cx; centers[o + 1] = cy; centers[o + 2] = cz;
            out_pos[o + 0] = cx; out_pos[o + 1] = cy; out_pos[o + 2] = cz;
        }
        par ^= 1;
    }
}

// ========================= Selection ==========================
// Exact K-nearest within radius r via binary search on uint(d2) bits.
// Fused: one kernel, 3 scale segments of 256 blocks each.
template <int K>
__device__ void select_body(
        const float* __restrict__ spx, const float* __restrict__ spy,
        const float* __restrict__ spz,
        const float* __restrict__ centers,
        int* __restrict__ nbr, int* __restrict__ nvalid,
        float r2, int blk) {
#pragma clang fp contract(off)
    const int cbase = blk * 32;
    const int lane = threadIdx.x & 63;
    const int wid = threadIdx.x >> 6;
    const unsigned kr2 = __float_as_uint(r2);

    for (int c = wid; c < 32; c += 4) {
        const int cid = cbase + c;
        const float cx = centers[cid * 3 + 0];
        const float cy = centers[cid * 3 + 1];
        const float cz = centers[cid * 3 + 2];
        unsigned key[64];
#pragma unroll
        for (int i = 0; i < 64; ++i) {
            int p = lane + i * 64;
            float dx = spx[p] - cx; float sx = dx * dx;
            float dy = spy[p] - cy; float sy = dy * dy;
            float dz = spz[p] - cz; float sz = dz * dz;
            float d2 = sx + sy; d2 = d2 + sz;
            key[i] = __float_as_uint(d2);
        }
        int c_cnt = 0;
#pragma unroll
        for (int i = 0; i < 64; ++i)
            c_cnt += __popcll(__ballot(key[i] <= kr2));

        const unsigned long long below = (1ull << lane) - 1ull;
        int nv;
        if (c_cnt <= K) {
            nv = c_cnt;
            int base = 0;
#pragma unroll
            for (int i = 0; i < 64; ++i) {
                unsigned long long m = __ballot(key[i] <= kr2);
                if (key[i] <= kr2) {
                    int slot = base + __popcll(m & below);
                    nbr[(size_t)cid * K + slot] = lane + i * 64;
                }
                base += __popcll(m);
            }
        } else {
            nv = K;
            unsigned lo = 0, hi = kr2;
            while (lo < hi) {
                unsigned mid = lo + ((hi - lo) >> 1);
                int cnt = 0;
#pragma unroll
                for (int i = 0; i < 64; ++i)
                    cnt += __popcll(__ballot(key[i] <= mid));
                if (cnt >= K) hi = mid; else lo = mid + 1;
            }
            const unsigned t = lo;  // K-th smallest key
            int m_cnt = 0;
#pragma unroll
            for (int i = 0; i < 64; ++i)
                m_cnt += __popcll(__ballot(key[i] < t));
            const int rem = K - m_cnt;
            int base = 0, ties = 0;
#pragma unroll
            for (int i = 0; i < 64; ++i) {
                unsigned long long lt = __ballot(key[i] < t);
                unsigned long long eq = __ballot(key[i] == t);
                if (key[i] < t) {
                    int slot = base + __popcll(lt & below);
                    nbr[(size_t)cid * K + slot] = lane + i * 64;
                } else if (key[i] == t) {
                    int tr = ties + __popcll(eq & below);
                    if (tr < rem) nbr[(size_t)cid * K + (m_cnt + tr)] = lane + i * 64;
                }
                base += __popcll(lt);
                ties += __popcll(eq);
            }
        }
        if (lane == 0) nvalid[cid] = nv;
    }
}

__global__ __launch_bounds__(256) void select_all(
        const float* __restrict__ pos,
        const float* __restrict__ centers,
        int* __restrict__ nbr0, int* __restrict__ nbr1, int* __restrict__ nbr2,
        int* __restrict__ nvalid) {
    __shared__ float spx[NP], spy[NP], spz[NP];
    const int blk = blockIdx.x;
    const int seg = blk >> 8;        // 0,1,2
    const int sblk = blk & 255;
    const int b = (sblk * 32) / NS;
    const float* pb = pos + (size_t)b * NP * 3;
    for (int p = threadIdx.x; p < NP; p += 256) {
        spx[p] = pb[p * 3 + 0];
        spy[p] = pb[p * 3 + 1];
        spz[p] = pb[p * 3 + 2];
    }
    __syncthreads();
    if (seg == 0)
        select_body<16>(spx, spy, spz, centers, nbr0, nvalid,
                        (float)(0.1 * 0.1), sblk);
    else if (seg == 1)
        select_body<32>(spx, spy, spz, centers, nbr1, nvalid + 8192,
                        (float)(0.2 * 0.2), sblk);
    else
        select_body<64>(spx, spy, spz, centers, nbr2, nvalid + 16384,
                        (float)(0.4 * 0.4), sblk);
}

// ===================== weight prep (fused, fp32 -> f16, [n][k], K-padded) ==
struct PrepArgs {
    const float* src[9];
    _Float16* dst[9];
    int kr[9], kp[9], nc[9];
};

__global__ __launch_bounds__(256) void prep_all(PrepArgs a) {
    const int m = blockIdx.y;
    const int kp = a.kp[m], kr = a.kr[m], nc = a.nc[m];
    const float* src = a.src[m];
    _Float16* dst = a.dst[m];
    const int tot = kp * nc;
    for (int i = blockIdx.x * 256 + threadIdx.x; i < tot; i += gridDim.x * 256) {
        int n = i / kp, k = i - n * kp;
        dst[i] = (k < kr) ? (_Float16)src[(size_t)k * nc + n] : (_Float16)0.f;
    }
}

// =========================== MFMA MLP ==============================
// Fused uber-kernel: 3 scale segments of 1024 blocks share one launch so
// the scales overlap on the device. LDS is a unioned dynamic buffer.
// One block = 4 waves splitting N 4 ways; weight fragments resident in VGPRs.
// mfma_f32_16x16x32_f16: A[m=lane&15][k=(lane>>4)*8+j],
// B[k=(lane>>4)*8+j][n=lane&15], D: col=lane&15, row=(lane>>4)*4+reg.
template <int M, int C1, int C2, int C3, int OFF, int NCTR>
__device__ void mlp_body(
        char* smem,
        const float* __restrict__ x, const float* __restrict__ pos,
        const float* __restrict__ centers,
        const int* __restrict__ nbr, const int* __restrict__ nvalid,
        const _Float16* __restrict__ wt1, const _Float16* __restrict__ wt2,
        const _Float16* __restrict__ wt3,
        const float* __restrict__ b1, const float* __restrict__ b2,
        const float* __restrict__ b3,
        float* __restrict__ out, int blk) {
    constexpr int K1P = 96;                 // 67 padded to 96
    constexpr int S1 = K1P + 8;             // 104 elems = 208 B
    constexpr int S2 = C1 + 8;
    constexpr int S3 = C2 + 8;
    constexpr int MT = M / 16;
    constexpr int NCH1 = C1 / 4, NCH2 = C2 / 4, NCH3 = C3 / 4;
    constexpr int NT1 = NCH1 / 16, NT2 = NCH2 / 16, NT3 = NCH3 / 16;
    constexpr int KT1 = K1P / 32, KT2 = C1 / 32, KT3 = C2 / 32;

    _Float16* feat = (_Float16*)smem;            // M*S1, 16B-aligned
    _Float16* h1 = feat + M * S1;
    _Float16* h2 = h1 + M * S2;
    int* outmax = (int*)(h2 + M * S3);           // C3 ints

    const int tid = threadIdx.x;
    const int lane = tid & 63;
    const int w = tid >> 6;
    const int lm = lane & 15;
    const int lq = lane >> 4;

    // ---- resident weight fragments + biases (per wave N-chunk) ----
    f16x8 wf1[NT1][KT1], wf2[NT2][KT2], wf3[NT3][KT3];
    float bb1[NT1], bb2[NT2], bb3[NT3];
#pragma unroll
    for (int nt = 0; nt < NT1; ++nt) {
        int n = w * NCH1 + nt * 16 + lm;
        bb1[nt] = b1[n];
#pragma unroll
        for (int kt = 0; kt < KT1; ++kt)
            wf1[nt][kt] = *(const f16x8*)(wt1 + (size_t)n * K1P + kt * 32 + lq * 8);
    }
#pragma unroll
    for (int nt = 0; nt < NT2; ++nt) {
        int n = w * NCH2 + nt * 16 + lm;
        bb2[nt] = b2[n];
#pragma unroll
        for (int kt = 0; kt < KT2; ++kt)
            wf2[nt][kt] = *(const f16x8*)(wt2 + (size_t)n * C1 + kt * 32 + lq * 8);
    }
#pragma unroll
    for (int nt = 0; nt < NT3; ++nt) {
        int n = w * NCH3 + nt * 16 + lm;
        bb3[nt] = b3[n];
#pragma unroll
        for (int kt = 0; kt < KT3; ++kt)
            wf3[nt][kt] = *(const f16x8*)(wt3 + (size_t)n * C2 + kt * 32 + lq * 8);
    }

    for (int cc = 0; cc < NCTR; ++cc) {
        const int cid = blk * NCTR + cc;
        const int bidx = cid >> 10;
        const int nv = nvalid[cid];
        const float cx = centers[cid * 3 + 0];
        const float cy = centers[cid * 3 + 1];
        const float cz = centers[cid * 3 + 2];
        for (int i = tid; i < C3; i += 256) outmax[i] = 0;

        // ---- gather pass A: x features, 16 lanes/row, float4 -> f16x4 ----
        // invalid rows (r >= nv) left stale: row-local through MFMA,
        // relu(NaN)=0, excluded from the max at layer 3.
#pragma unroll
        for (int it = tid; it < M * 16; it += 256) {
            const int r = it >> 4, sub = it & 15;
            if (r < nv) {
                int pt = nbr[(size_t)cid * M + r];
                float4 v = *(const float4*)(x + ((size_t)(bidx * NP) + pt) * 64 + sub * 4);
                f16x4 hv = {(_Float16)v.x, (_Float16)v.y, (_Float16)v.z, (_Float16)v.w};
                *(f16x4*)(feat + r * S1 + sub * 4) = hv;
            }
        }
        // ---- gather pass B: pos-rel + zero K-pad (cols 64..95) ----
#pragma unroll
        for (int it = tid; it < M * 4; it += 256) {
            const int r = it >> 2, q = it & 3;
            f16x8 z = {(_Float16)0.f, (_Float16)0.f, (_Float16)0.f, (_Float16)0.f,
                       (_Float16)0.f, (_Float16)0.f, (_Float16)0.f, (_Float16)0.f};
            if (q == 0 && r < nv) {
                int pt = nbr[(size_t)cid * M + r];
                const float* pr = pos + ((size_t)(bidx * NP) + pt) * 3;
                z[0] = (_Float16)(pr[0] - cx);
                z[1] = (_Float16)(pr[1] - cy);
                z[2] = (_Float16)(pr[2] - cz);
            }
            *(f16x8*)(feat + r * S1 + 64 + q * 8) = z;
        }
        __syncthreads();

        // ---- layer 1: feat[M x 96] -> h1[M x C1] ----
#pragma unroll
        for (int mt = 0; mt < MT; ++mt) {
            f16x8 a[KT1];
#pragma unroll
            for (int kt = 0; kt < KT1; ++kt)
                a[kt] = *(const f16x8*)(feat + (mt * 16 + lm) * S1 + kt * 32 + lq * 8);
#pragma unroll
            for (int nt = 0; nt < NT1; ++nt) {
                f32x4 acc = {bb1[nt], bb1[nt], bb1[nt], bb1[nt]};
#pragma unroll
                for (int kt = 0; kt < KT1; ++kt)
                    acc = __builtin_amdgcn_mfma_f32_16x16x32_f16(a[kt], wf1[nt][kt], acc, 0, 0, 0);
                const int gc = w * NCH1 + nt * 16 + lm;
#pragma unroll
                for (int rg = 0; rg < 4; ++rg)
                    h1[(mt * 16 + lq * 4 + rg) * S2 + gc] = (_Float16)fmaxf(acc[rg], 0.f);
            }
        }
        __syncthreads();

        // ---- layer 2: h1[M x C1] -> h2[M x C2] ----
#pragma unroll
        for (int mt = 0; mt < MT; ++mt) {
            f16x8 a[KT2];
#pragma unroll
            for (int kt = 0; kt < KT2; ++kt)
                a[kt] = *(const f16x8*)(h1 + (mt * 16 + lm) * S2 + kt * 32 + lq * 8);
#pragma unroll
            for (int nt = 0; nt < NT2; ++nt) {
                f32x4 acc = {bb2[nt], bb2[nt], bb2[nt], bb2[nt]};
#pragma unroll
                for (int kt = 0; kt < KT2; ++kt)
                    acc = __builtin_amdgcn_mfma_f32_16x16x32_f16(a[kt], wf2[nt][kt], acc, 0, 0, 0);
                const int gc = w * NCH2 + nt * 16 + lm;
#pragma unroll
                for (int rg = 0; rg < 4; ++rg)
                    h2[(mt * 16 + lq * 4 + rg) * S3 + gc] = (_Float16)fmaxf(acc[rg], 0.f);
            }
        }
        __syncthreads();

        // ---- layer 3 + masked max ----
#pragma unroll
        for (int mt = 0; mt < MT; ++mt) {
            f16x8 a[KT3];
#pragma unroll
            for (int kt = 0; kt < KT3; ++kt)
                a[kt] = *(const f16x8*)(h2 + (mt * 16 + lm) * S3 + kt * 32 + lq * 8);
#pragma unroll
            for (int nt = 0; nt < NT3; ++nt) {
                f32x4 acc = {bb3[nt], bb3[nt], bb3[nt], bb3[nt]};
#pragma unroll
                for (int kt = 0; kt < KT3; ++kt)
                    acc = __builtin_amdgcn_mfma_f32_16x16x32_f16(a[kt], wf3[nt][kt], acc, 0, 0, 0);
                float mx = -1.f;
#pragma unroll
                for (int rg = 0; rg < 4; ++rg) {
                    int row = mt * 16 + lq * 4 + rg;
                    float v = fmaxf(acc[rg], 0.f);
                    if (row < nv) mx = fmaxf(mx, v);
                }
                mx = fmaxf(mx, __shfl_xor(mx, 16));
                mx = fmaxf(mx, __shfl_xor(mx, 32));
                if (lane < 16)
                    atomicMax(&outmax[w * NCH3 + nt * 16 + lm], __float_as_int(mx));
            }
        }
        __syncthreads();
        for (int i = tid; i < C3; i += 256)
            out[(size_t)cid * 640 + OFF + i] = __int_as_float(outmax[i]);
        __syncthreads();
    }
}

struct MlpW {
    const _Float16* w[9];
    const float* bias[9];
};

__global__ __launch_bounds__(256, 2) void mlp_all(
        const float* __restrict__ x, const float* __restrict__ pos,
        const float* __restrict__ centers,
        const int* __restrict__ nbr0, const int* __restrict__ nbr1,
        const int* __restrict__ nbr2, const int* __restrict__ nval,
        MlpW ww, float* __restrict__ out) {
    extern __shared__ char smem[];
    const int blk = blockIdx.x;
    if (blk < 1024)
        mlp_body<16, 64, 64, 128, 0, 8>(smem, x, pos, centers, nbr0, nval,
            ww.w[0], ww.w[1], ww.w[2], ww.bias[0], ww.bias[1], ww.bias[2], out, blk);
    else if (blk < 2048)
        mlp_body<32, 128, 128, 256, 128, 8>(smem, x, pos, centers, nbr1, nval + 8192,
            ww.w[3], ww.w[4], ww.w[5], ww.bias[3], ww.bias[4], ww.bias[5], out, blk - 1024);
    else
        mlp_body<64, 128, 128, 256, 384, 8>(smem, x, pos, centers, nbr2, nval + 16384,
            ww.w[6], ww.w[7], ww.w[8], ww.bias[6], ww.bias[7], ww.bias[8], out, blk - 2048);
}

// ========================= launcher ===========================
extern "C" void kernel_launch(void* const* d_in, const int* in_sizes, int n_in,
                              void* d_out, int out_size, void* d_ws, size_t ws_size,
                              hipStream_t stream) {
    const float* x = (const float*)d_in[0];
    const float* pos = (const float*)d_in[1];
    const float* W0_0 = (const float*)d_in[3];
    const float* b0_0 = (const float*)d_in[4];
    const float* W0_1 = (const float*)d_in[5];
    const float* b0_1 = (const float*)d_in[6];
    const float* W0_2 = (const float*)d_in[7];
    const float* b0_2 = (const float*)d_in[8];
    const float* W1_0 = (const float*)d_in[9];
    const float* b1_0 = (const float*)d_in[10];
    const float* W1_1 = (const float*)d_in[11];
    const float* b1_1 = (const float*)d_in[12];
    const float* W1_2 = (const float*)d_in[13];
    const float* b1_2 = (const float*)d_in[14];
    const float* W2_0 = (const float*)d_in[15];
    const float* b2_0 = (const float*)d_in[16];
    const float* W2_1 = (const float*)d_in[17];
    const float* b2_1 = (const float*)d_in[18];
    const float* W2_2 = (const float*)d_in[19];
    const float* b2_2 = (const float*)d_in[20];

    float* out = (float*)d_out;
    char* ws = (char*)d_ws;
    float* centers = (float*)(ws + 0);                 //  98304 B
    int* nbr0 = (int*)(ws + 98304);                    //  524288 B
    int* nbr1 = (int*)(ws + 622592);                   //  1048576 B
    int* nbr2 = (int*)(ws + 1671168);                  //  2097152 B
    int* nval = (int*)(ws + 3768320);                  //  98304 B
    // f16 transposed weights
    _Float16* w0t1 = (_Float16*)(ws + 3866624);        //  64*96  = 12288 B
    _Float16* w0t2 = (_Float16*)(ws + 3878912);        //  64*64  =  8192 B
    _Float16* w0t3 = (_Float16*)(ws + 3887104);        // 128*64  = 16384 B
    _Float16* w1t1 = (_Float16*)(ws + 3903488);        // 128*96  = 24576 B
    _Float16* w1t2 = (_Float16*)(ws + 3928064);        // 128*128 = 32768 B
    _Float16* w1t3 = (_Float16*)(ws + 3960832);        // 256*128 = 65536 B
    _Float16* w2t1 = (_Float16*)(ws + 4026368);
    _Float16* w2t2 = (_Float16*)(ws + 4050944);
    _Float16* w2t3 = (_Float16*)(ws + 4083712);        // end 4149248 B

    float* out_pos = out + (size_t)8192 * 640;
    float* out_batch = out_pos + (size_t)8192 * 3;

    fps_kernel<<<dim3(NB), dim3(256), 0, stream>>>(pos, centers, out_pos, out_batch);

    select_all<<<dim3(768), dim3(256), 0, stream>>>(pos, centers, nbr0, nbr1, nbr2, nval);

    PrepArgs pa;
    pa.src[0] = W0_0; pa.dst[0] = w0t1; pa.kr[0] = 67;  pa.kp[0] = 96;  pa.nc[0] = 64;
    pa.src[1] = W0_1; pa.dst[1] = w0t2; pa.kr[1] = 64;  pa.kp[1] = 64;  pa.nc[1] = 64;
    pa.src[2] = W0_2; pa.dst[2] = w0t3; pa.kr[2] = 64;  pa.kp[2] = 64;  pa.nc[2] = 128;
    pa.src[3] = W1_0; pa.dst[3] = w1t1; pa.kr[3] = 67;  pa.kp[3] = 96;  pa.nc[3] = 128;
    pa.src[4] = W1_1; pa.dst[4] = w1t2; pa.kr[4] = 128; pa.kp[4] = 128; pa.nc[4] = 128;
    pa.src[5] = W1_2; pa.dst[5] = w1t3; pa.kr[5] = 128; pa.kp[5] = 128; pa.nc[5] = 256;
    pa.src[6] = W2_0; pa.dst[6] = w2t1; pa.kr[6] = 67;  pa.kp[6] = 96;  pa.nc[6] = 128;
    pa.src[7] = W2_1; pa.dst[7] = w2t2; pa.kr[7] = 128; pa.kp[7] = 128; pa.nc[7] = 128;
    pa.src[8] = W2_2; pa.dst[8] = w2t3; pa.kr[8] = 128; pa.kp[8] = 128; pa.nc[8] = 256;
    prep_all<<<dim3(64, 9), dim3(256), 0, stream>>>(pa);

    MlpW ww;
    ww.w[0] = w0t1; ww.w[1] = w0t2; ww.w[2] = w0t3;
    ww.w[3] = w1t1; ww.w[4] = w1t2; ww.w[5] = w1t3;
    ww.w[6] = w2t1; ww.w[7] = w2t2; ww.w[8] = w2t3;
    ww.bias[0] = b0_0; ww.bias[1] = b0_1; ww.bias[2] = b0_2;
    ww.bias[3] = b1_0; ww.bias[4] = b1_1; ww.bias[5] = b1_2;
    ww.bias[6] = b2_0; ww.bias[7] = b2_1; ww.bias[8] = b2_2;

    // dynamic LDS = scale-2 footprint: 64*104*2 + 64*136*2*2 + 256*4 = 49152 B
    mlp_all<<<dim3(3072), dim3(256), 49152, stream>>>(
        x, pos, centers, nbr0, nbr1, nbr2, nval, ww, out);
}

// Round 8
// 1801.924 us; speedup vs baseline: 1.1746x; 1.1746x over previous
//
#include <hip/hip_runtime.h>

#define NB 8
#define NP 4096
#define NS 1024

typedef _Float16 f16x8 __attribute__((ext_vector_type(8)));
typedef _Float16 f16x4 __attribute__((ext_vector_type(4)));
typedef float f32x4 __attribute__((ext_vector_type(4)));

// DPP-fused max step: v = max(v, dpp_move(v, ctrl)). bound_ctrl=false keeps
// old value on invalid lanes -> max(v,v)=v, harmless.
#define DPP_MAX(v, ctrl)                                                     \
    v = fmaxf(v, __int_as_float(__builtin_amdgcn_update_dpp(                 \
                __float_as_int(v), __float_as_int(v), (ctrl), 0xf, 0xf, false)))

// ============================ FPS =============================
// ROUND-5 MEASURED OPTIMUM (730 us) — do not "improve" without a counter
// theory. 512 threads (8 waves) x 8 CONTIGUOUS points/thread (p = tid*8+j):
// 32-float state fits allocated VGPRs (no AGPR stash — the 256x16 variants
// at 48 VGPR pay v_accvgpr traffic per access and measure 810-1094 us).
// In-loop coordinate carries (cndmask), DPP value-max, ballot+ffs winner,
// ONE barrier, all-threads redundant 8-slot combine (serialized combine +
// 2nd barrier measured +240 us — r6).
__global__ __launch_bounds__(512, 1) void fps_kernel(
        const float* __restrict__ pos,
        float* __restrict__ centers,
        float* __restrict__ out_pos,
        float* __restrict__ out_batch) {
#pragma clang fp contract(off)
    const int b = blockIdx.x;
    const int tid = threadIdx.x;
    const int lane = tid & 63;
    const int wid = tid >> 6;
    __shared__ float4 slot[2][8];   // [parity][wave]

    const float* pb = pos + (size_t)b * NP * 3;
    float px[8], py[8], pz[8], md[8];
    {
        const float4* pv = (const float4*)(pb + tid * 24);
        float4 q0 = pv[0], q1 = pv[1], q2 = pv[2];
        float4 q3 = pv[3], q4 = pv[4], q5 = pv[5];
        px[0] = q0.x; py[0] = q0.y; pz[0] = q0.z;
        px[1] = q0.w; py[1] = q1.x; pz[1] = q1.y;
        px[2] = q1.z; py[2] = q1.w; pz[2] = q2.x;
        px[3] = q2.y; py[3] = q2.z; pz[3] = q2.w;
        px[4] = q3.x; py[4] = q3.y; pz[4] = q3.z;
        px[5] = q3.w; py[5] = q4.x; pz[5] = q4.y;
        px[6] = q4.z; py[6] = q4.w; pz[6] = q5.x;
        px[7] = q5.y; py[7] = q5.z; pz[7] = q5.w;
    }
#pragma unroll
    for (int j = 0; j < 8; ++j) md[j] = __builtin_inff();
    for (int t = tid; t < NS; t += 512) out_batch[b * NS + t] = (float)b;

    float cx = pb[0], cy = pb[1], cz = pb[2];
    if (tid == 0) {
        size_t o = (size_t)(b * NS) * 3;
        centers[o + 0] = cx; centers[o + 1] = cy; centers[o + 2] = cz;
        out_pos[o + 0] = cx; out_pos[o + 1] = cy; out_pos[o + 2] = cz;
    }

    int par = 0;
    for (int t = 1; t < NS; ++t) {
        float bv = -1.0f, bx = cx, by = cy, bz = cz;
#pragma unroll
        for (int j = 0; j < 8; ++j) {
            float dx = px[j] - cx; float sx = dx * dx;
            float dy = py[j] - cy; float sy = dy * dy;
            float dz = pz[j] - cz; float sz = dz * dz;
            float d = sx + sy; d = d + sz;
            float m = fminf(md[j], d);
            md[j] = m;
            bool c = m > bv;                 // strict >: first j wins ties
            bv = c ? m : bv;
            bx = c ? px[j] : bx;
            by = c ? py[j] : by;
            bz = c ? pz[j] : bz;
        }
        // wave max via DPP (result valid in lane 63), then SGPR broadcast
        float v = bv;
        DPP_MAX(v, 0x111);   // row_shr:1
        DPP_MAX(v, 0x112);   // row_shr:2
        DPP_MAX(v, 0x114);   // row_shr:4
        DPP_MAX(v, 0x118);   // row_shr:8
        DPP_MAX(v, 0x142);   // row_bcast:15
        DPP_MAX(v, 0x143);   // row_bcast:31
        const float mx = __int_as_float(
            __builtin_amdgcn_readlane(__float_as_int(v), 63));
        unsigned long long tie = __ballot(bv == mx);
        if (lane == __ffsll(tie) - 1)        // lowest lane among ties
            slot[par][wid] = make_float4(mx, bx, by, bz);
        __syncthreads();
        float4 s0 = slot[par][0], s1 = slot[par][1];
        float4 s2 = slot[par][2], s3 = slot[par][3];
        float4 s4 = slot[par][4], s5 = slot[par][5];
        float4 s6 = slot[par][6], s7 = slot[par][7];
        float4 a01 = (s1.x > s0.x) ? s1 : s0;   // ties keep lower wave
        float4 a23 = (s3.x > s2.x) ? s3 : s2;
        float4 a45 = (s5.x > s4.x) ? s5 : s4;
        float4 a67 = (s7.x > s6.x) ? s7 : s6;
        float4 b03 = (a23.x > a01.x) ? a23 : a01;
        float4 b47 = (a67.x > a45.x) ? a67 : a45;
        float4 wn = (b47.x > b03.x) ? b47 : b03;
        cx = wn.y; cy = wn.z; cz = wn.w;
        if (tid == 0) {
            size_t o = (size_t)(b * NS + t) * 3;
            centers[o + 0] = cx; centers[o + 1] = cy; centers[o + 2] = cz;
            out_pos[o + 0] = cx; out_pos[o + 1] = cy; out_pos[o + 2] = cz;
        }
        par ^= 1;
    }
}

// ========================= Selection ==========================
// Exact K-nearest within radius r via binary search on uint(d2) bits.
// Fused: one kernel, 3 scale segments of 256 blocks each.
template <int K>
__device__ void select_body(
        const float* __restrict__ spx, const float* __restrict__ spy,
        const float* __restrict__ spz,
        const float* __restrict__ centers,
        int* __restrict__ nbr, int* __restrict__ nvalid,
        float r2, int blk) {
#pragma clang fp contract(off)
    const int cbase = blk * 32;
    const int lane = threadIdx.x & 63;
    const int wid = threadIdx.x >> 6;
    const unsigned kr2 = __float_as_uint(r2);

    for (int c = wid; c < 32; c += 4) {
        const int cid = cbase + c;
        const float cx = centers[cid * 3 + 0];
        const float cy = centers[cid * 3 + 1];
        const float cz = centers[cid * 3 + 2];
        unsigned key[64];
#pragma unroll
        for (int i = 0; i < 64; ++i) {
            int p = lane + i * 64;
            float dx = spx[p] - cx; float sx = dx * dx;
            float dy = spy[p] - cy; float sy = dy * dy;
            float dz = spz[p] - cz; float sz = dz * dz;
            float d2 = sx + sy; d2 = d2 + sz;
            key[i] = __float_as_uint(d2);
        }
        int c_cnt = 0;
#pragma unroll
        for (int i = 0; i < 64; ++i)
            c_cnt += __popcll(__ballot(key[i] <= kr2));

        const unsigned long long below = (1ull << lane) - 1ull;
        int nv;
        if (c_cnt <= K) {
            nv = c_cnt;
            int base = 0;
#pragma unroll
            for (int i = 0; i < 64; ++i) {
                unsigned long long m = __ballot(key[i] <= kr2);
                if (key[i] <= kr2) {
                    int slot = base + __popcll(m & below);
                    nbr[(size_t)cid * K + slot] = lane + i * 64;
                }
                base += __popcll(m);
            }
        } else {
            nv = K;
            unsigned lo = 0, hi = kr2;
            while (lo < hi) {
                unsigned mid = lo + ((hi - lo) >> 1);
                int cnt = 0;
#pragma unroll
                for (int i = 0; i < 64; ++i)
                    cnt += __popcll(__ballot(key[i] <= mid));
                if (cnt >= K) hi = mid; else lo = mid + 1;
            }
            const unsigned t = lo;  // K-th smallest key
            int m_cnt = 0;
#pragma unroll
            for (int i = 0; i < 64; ++i)
                m_cnt += __popcll(__ballot(key[i] < t));
            const int rem = K - m_cnt;
            int base = 0, ties = 0;
#pragma unroll
            for (int i = 0; i < 64; ++i) {
                unsigned long long lt = __ballot(key[i] < t);
                unsigned long long eq = __ballot(key[i] == t);
                if (key[i] < t) {
                    int slot = base + __popcll(lt & below);
                    nbr[(size_t)cid * K + slot] = lane + i * 64;
                } else if (key[i] == t) {
                    int tr = ties + __popcll(eq & below);
                    if (tr < rem) nbr[(size_t)cid * K + (m_cnt + tr)] = lane + i * 64;
                }
                base += __popcll(lt);
                ties += __popcll(eq);
            }
        }
        if (lane == 0) nvalid[cid] = nv;
    }
}

__global__ __launch_bounds__(256) void select_all(
        const float* __restrict__ pos,
        const float* __restrict__ centers,
        int* __restrict__ nbr0, int* __restrict__ nbr1, int* __restrict__ nbr2,
        int* __restrict__ nvalid) {
    __shared__ float spx[NP], spy[NP], spz[NP];
    const int blk = blockIdx.x;
    const int seg = blk >> 8;        // 0,1,2
    const int sblk = blk & 255;
    const int b = (sblk * 32) / NS;
    const float* pb = pos + (size_t)b * NP * 3;
    for (int p = threadIdx.x; p < NP; p += 256) {
        spx[p] = pb[p * 3 + 0];
        spy[p] = pb[p * 3 + 1];
        spz[p] = pb[p * 3 + 2];
    }
    __syncthreads();
    if (seg == 0)
        select_body<16>(spx, spy, spz, centers, nbr0, nvalid,
                        (float)(0.1 * 0.1), sblk);
    else if (seg == 1)
        select_body<32>(spx, spy, spz, centers, nbr1, nvalid + 8192,
                        (float)(0.2 * 0.2), sblk);
    else
        select_body<64>(spx, spy, spz, centers, nbr2, nvalid + 16384,
                        (float)(0.4 * 0.4), sblk);
}

// ===================== weight prep (fused, fp32 -> f16, [n][k], K-padded) ==
struct PrepArgs {
    const float* src[9];
    _Float16* dst[9];
    int kr[9], kp[9], nc[9];
};

__global__ __launch_bounds__(256) void prep_all(PrepArgs a) {
    const int m = blockIdx.y;
    const int kp = a.kp[m], kr = a.kr[m], nc = a.nc[m];
    const float* src = a.src[m];
    _Float16* dst = a.dst[m];
    const int tot = kp * nc;
    for (int i = blockIdx.x * 256 + threadIdx.x; i < tot; i += gridDim.x * 256) {
        int n = i / kp, k = i - n * kp;
        dst[i] = (k < kr) ? (_Float16)src[(size_t)k * nc + n] : (_Float16)0.f;
    }
}

// =========================== MFMA MLP ==============================
// Fused uber-kernel: 3 scale segments of 1024 blocks share one launch so
// the scales overlap on the device. LDS is a unioned dynamic buffer.
// One block = 4 waves splitting N 4 ways; weight fragments resident in VGPRs.
// mfma_f32_16x16x32_f16: A[m=lane&15][k=(lane>>4)*8+j],
// B[k=(lane>>4)*8+j][n=lane&15], D: col=lane&15, row=(lane>>4)*4+reg.
template <int M, int C1, int C2, int C3, int OFF, int NCTR>
__device__ void mlp_body(
        char* smem,
        const float* __restrict__ x, const float* __restrict__ pos,
        const float* __restrict__ centers,
        const int* __restrict__ nbr, const int* __restrict__ nvalid,
        const _Float16* __restrict__ wt1, const _Float16* __restrict__ wt2,
        const _Float16* __restrict__ wt3,
        const float* __restrict__ b1, const float* __restrict__ b2,
        const float* __restrict__ b3,
        float* __restrict__ out, int blk) {
    constexpr int K1P = 96;                 // 67 padded to 96
    constexpr int S1 = K1P + 8;             // 104 elems = 208 B
    constexpr int S2 = C1 + 8;
    constexpr int S3 = C2 + 8;
    constexpr int MT = M / 16;
    constexpr int NCH1 = C1 / 4, NCH2 = C2 / 4, NCH3 = C3 / 4;
    constexpr int NT1 = NCH1 / 16, NT2 = NCH2 / 16, NT3 = NCH3 / 16;
    constexpr int KT1 = K1P / 32, KT2 = C1 / 32, KT3 = C2 / 32;

    _Float16* feat = (_Float16*)smem;            // M*S1, 16B-aligned
    _Float16* h1 = feat + M * S1;
    _Float16* h2 = h1 + M * S2;
    int* outmax = (int*)(h2 + M * S3);           // C3 ints

    const int tid = threadIdx.x;
    const int lane = tid & 63;
    const int w = tid >> 6;
    const int lm = lane & 15;
    const int lq = lane >> 4;

    // ---- resident weight fragments + biases (per wave N-chunk) ----
    f16x8 wf1[NT1][KT1], wf2[NT2][KT2], wf3[NT3][KT3];
    float bb1[NT1], bb2[NT2], bb3[NT3];
#pragma unroll
    for (int nt = 0; nt < NT1; ++nt) {
        int n = w * NCH1 + nt * 16 + lm;
        bb1[nt] = b1[n];
#pragma unroll
        for (int kt = 0; kt < KT1; ++kt)
            wf1[nt][kt] = *(const f16x8*)(wt1 + (size_t)n * K1P + kt * 32 + lq * 8);
    }
#pragma unroll
    for (int nt = 0; nt < NT2; ++nt) {
        int n = w * NCH2 + nt * 16 + lm;
        bb2[nt] = b2[n];
#pragma unroll
        for (int kt = 0; kt < KT2; ++kt)
            wf2[nt][kt] = *(const f16x8*)(wt2 + (size_t)n * C1 + kt * 32 + lq * 8);
    }
#pragma unroll
    for (int nt = 0; nt < NT3; ++nt) {
        int n = w * NCH3 + nt * 16 + lm;
        bb3[nt] = b3[n];
#pragma unroll
        for (int kt = 0; kt < KT3; ++kt)
            wf3[nt][kt] = *(const f16x8*)(wt3 + (size_t)n * C2 + kt * 32 + lq * 8);
    }

    for (int cc = 0; cc < NCTR; ++cc) {
        const int cid = blk * NCTR + cc;
        const int bidx = cid >> 10;
        const int nv = nvalid[cid];
        const float cx = centers[cid * 3 + 0];
        const float cy = centers[cid * 3 + 1];
        const float cz = centers[cid * 3 + 2];
        for (int i = tid; i < C3; i += 256) outmax[i] = 0;

        // ---- gather pass A: x features, 16 lanes/row, float4 -> f16x4 ----
        // invalid rows (r >= nv) left stale: row-local through MFMA,
        // relu(NaN)=0, excluded from the max at layer 3.
#pragma unroll
        for (int it = tid; it < M * 16; it += 256) {
            const int r = it >> 4, sub = it & 15;
            if (r < nv) {
                int pt = nbr[(size_t)cid * M + r];
                float4 v = *(const float4*)(x + ((size_t)(bidx * NP) + pt) * 64 + sub * 4);
                f16x4 hv = {(_Float16)v.x, (_Float16)v.y, (_Float16)v.z, (_Float16)v.w};
                *(f16x4*)(feat + r * S1 + sub * 4) = hv;
            }
        }
        // ---- gather pass B: pos-rel + zero K-pad (cols 64..95) ----
#pragma unroll
        for (int it = tid; it < M * 4; it += 256) {
            const int r = it >> 2, q = it & 3;
            f16x8 z = {(_Float16)0.f, (_Float16)0.f, (_Float16)0.f, (_Float16)0.f,
                       (_Float16)0.f, (_Float16)0.f, (_Float16)0.f, (_Float16)0.f};
            if (q == 0 && r < nv) {
                int pt = nbr[(size_t)cid * M + r];
                const float* pr = pos + ((size_t)(bidx * NP) + pt) * 3;
                z[0] = (_Float16)(pr[0] - cx);
                z[1] = (_Float16)(pr[1] - cy);
                z[2] = (_Float16)(pr[2] - cz);
            }
            *(f16x8*)(feat + r * S1 + 64 + q * 8) = z;
        }
        __syncthreads();

        // ---- layer 1: feat[M x 96] -> h1[M x C1] ----
#pragma unroll
        for (int mt = 0; mt < MT; ++mt) {
            f16x8 a[KT1];
#pragma unroll
            for (int kt = 0; kt < KT1; ++kt)
                a[kt] = *(const f16x8*)(feat + (mt * 16 + lm) * S1 + kt * 32 + lq * 8);
#pragma unroll
            for (int nt = 0; nt < NT1; ++nt) {
                f32x4 acc = {bb1[nt], bb1[nt], bb1[nt], bb1[nt]};
#pragma unroll
                for (int kt = 0; kt < KT1; ++kt)
                    acc = __builtin_amdgcn_mfma_f32_16x16x32_f16(a[kt], wf1[nt][kt], acc, 0, 0, 0);
                const int gc = w * NCH1 + nt * 16 + lm;
#pragma unroll
                for (int rg = 0; rg < 4; ++rg)
                    h1[(mt * 16 + lq * 4 + rg) * S2 + gc] = (_Float16)fmaxf(acc[rg], 0.f);
            }
        }
        __syncthreads();

        // ---- layer 2: h1[M x C1] -> h2[M x C2] ----
#pragma unroll
        for (int mt = 0; mt < MT; ++mt) {
            f16x8 a[KT2];
#pragma unroll
            for (int kt = 0; kt < KT2; ++kt)
                a[kt] = *(const f16x8*)(h1 + (mt * 16 + lm) * S2 + kt * 32 + lq * 8);
#pragma unroll
            for (int nt = 0; nt < NT2; ++nt) {
                f32x4 acc = {bb2[nt], bb2[nt], bb2[nt], bb2[nt]};
#pragma unroll
                for (int kt = 0; kt < KT2; ++kt)
                    acc = __builtin_amdgcn_mfma_f32_16x16x32_f16(a[kt], wf2[nt][kt], acc, 0, 0, 0);
                const int gc = w * NCH2 + nt * 16 + lm;
#pragma unroll
                for (int rg = 0; rg < 4; ++rg)
                    h2[(mt * 16 + lq * 4 + rg) * S3 + gc] = (_Float16)fmaxf(acc[rg], 0.f);
            }
        }
        __syncthreads();

        // ---- layer 3 + masked max ----
#pragma unroll
        for (int mt = 0; mt < MT; ++mt) {
            f16x8 a[KT3];
#pragma unroll
            for (int kt = 0; kt < KT3; ++kt)
                a[kt] = *(const f16x8*)(h2 + (mt * 16 + lm) * S3 + kt * 32 + lq * 8);
#pragma unroll
            for (int nt = 0; nt < NT3; ++nt) {
                f32x4 acc = {bb3[nt], bb3[nt], bb3[nt], bb3[nt]};
#pragma unroll
                for (int kt = 0; kt < KT3; ++kt)
                    acc = __builtin_amdgcn_mfma_f32_16x16x32_f16(a[kt], wf3[nt][kt], acc, 0, 0, 0);
                float mx = -1.f;
#pragma unroll
                for (int rg = 0; rg < 4; ++rg) {
                    int row = mt * 16 + lq * 4 + rg;
                    float v = fmaxf(acc[rg], 0.f);
                    if (row < nv) mx = fmaxf(mx, v);
                }
                mx = fmaxf(mx, __shfl_xor(mx, 16));
                mx = fmaxf(mx, __shfl_xor(mx, 32));
                if (lane < 16)
                    atomicMax(&outmax[w * NCH3 + nt * 16 + lm], __float_as_int(mx));
            }
        }
        __syncthreads();
        for (int i = tid; i < C3; i += 256)
            out[(size_t)cid * 640 + OFF + i] = __int_as_float(outmax[i]);
        __syncthreads();
    }
}

struct MlpW {
    const _Float16* w[9];
    const float* bias[9];
};

__global__ __launch_bounds__(256, 2) void mlp_all(
        const float* __restrict__ x, const float* __restrict__ pos,
        const float* __restrict__ centers,
        const int* __restrict__ nbr0, const int* __restrict__ nbr1,
        const int* __restrict__ nbr2, const int* __restrict__ nval,
        MlpW ww, float* __restrict__ out) {
    extern __shared__ char smem[];
    const int blk = blockIdx.x;
    if (blk < 1024)
        mlp_body<16, 64, 64, 128, 0, 8>(smem, x, pos, centers, nbr0, nval,
            ww.w[0], ww.w[1], ww.w[2], ww.bias[0], ww.bias[1], ww.bias[2], out, blk);
    else if (blk < 2048)
        mlp_body<32, 128, 128, 256, 128, 8>(smem, x, pos, centers, nbr1, nval + 8192,
            ww.w[3], ww.w[4], ww.w[5], ww.bias[3], ww.bias[4], ww.bias[5], out, blk - 1024);
    else
        mlp_body<64, 128, 128, 256, 384, 8>(smem, x, pos, centers, nbr2, nval + 16384,
            ww.w[6], ww.w[7], ww.w[8], ww.bias[6], ww.bias[7], ww.bias[8], out, blk - 2048);
}

// ========================= launcher ===========================
extern "C" void kernel_launch(void* const* d_in, const int* in_sizes, int n_in,
                              void* d_out, int out_size, void* d_ws, size_t ws_size,
                              hipStream_t stream) {
    const float* x = (const float*)d_in[0];
    const float* pos = (const float*)d_in[1];
    const float* W0_0 = (const float*)d_in[3];
    const float* b0_0 = (const float*)d_in[4];
    const float* W0_1 = (const float*)d_in[5];
    const float* b0_1 = (const float*)d_in[6];
    const float* W0_2 = (const float*)d_in[7];
    const float* b0_2 = (const float*)d_in[8];
    const float* W1_0 = (const float*)d_in[9];
    const float* b1_0 = (const float*)d_in[10];
    const float* W1_1 = (const float*)d_in[11];
    const float* b1_1 = (const float*)d_in[12];
    const float* W1_2 = (const float*)d_in[13];
    const float* b1_2 = (const float*)d_in[14];
    const float* W2_0 = (const float*)d_in[15];
    const float* b2_0 = (const float*)d_in[16];
    const float* W2_1 = (const float*)d_in[17];
    const float* b2_1 = (const float*)d_in[18];
    const float* W2_2 = (const float*)d_in[19];
    const float* b2_2 = (const float*)d_in[20];

    float* out = (float*)d_out;
    char* ws = (char*)d_ws;
    float* centers = (float*)(ws + 0);                 //  98304 B
    int* nbr0 = (int*)(ws + 98304);                    //  524288 B
    int* nbr1 = (int*)(ws + 622592);                   //  1048576 B
    int* nbr2 = (int*)(ws + 1671168);                  //  2097152 B
    int* nval = (int*)(ws + 3768320);                  //  98304 B
    // f16 transposed weights
    _Float16* w0t1 = (_Float16*)(ws + 3866624);        //  64*96  = 12288 B
    _Float16* w0t2 = (_Float16*)(ws + 3878912);        //  64*64  =  8192 B
    _Float16* w0t3 = (_Float16*)(ws + 3887104);        // 128*64  = 16384 B
    _Float16* w1t1 = (_Float16*)(ws + 3903488);        // 128*96  = 24576 B
    _Float16* w1t2 = (_Float16*)(ws + 3928064);        // 128*128 = 32768 B
    _Float16* w1t3 = (_Float16*)(ws + 3960832);        // 256*128 = 65536 B
    _Float16* w2t1 = (_Float16*)(ws + 4026368);
    _Float16* w2t2 = (_Float16*)(ws + 4050944);
    _Float16* w2t3 = (_Float16*)(ws + 4083712);        // end 4149248 B

    float* out_pos = out + (size_t)8192 * 640;
    float* out_batch = out_pos + (size_t)8192 * 3;

    fps_kernel<<<dim3(NB), dim3(512), 0, stream>>>(pos, centers, out_pos, out_batch);

    select_all<<<dim3(768), dim3(256), 0, stream>>>(pos, centers, nbr0, nbr1, nbr2, nval);

    PrepArgs pa;
    pa.src[0] = W0_0; pa.dst[0] = w0t1; pa.kr[0] = 67;  pa.kp[0] = 96;  pa.nc[0] = 64;
    pa.src[1] = W0_1; pa.dst[1] = w0t2; pa.kr[1] = 64;  pa.kp[1] = 64;  pa.nc[1] = 64;
    pa.src[2] = W0_2; pa.dst[2] = w0t3; pa.kr[2] = 64;  pa.kp[2] = 64;  pa.nc[2] = 128;
    pa.src[3] = W1_0; pa.dst[3] = w1t1; pa.kr[3] = 67;  pa.kp[3] = 96;  pa.nc[3] = 128;
    pa.src[4] = W1_1; pa.dst[4] = w1t2; pa.kr[4] = 128; pa.kp[4] = 128; pa.nc[4] = 128;
    pa.src[5] = W1_2; pa.dst[5] = w1t3; pa.kr[5] = 128; pa.kp[5] = 128; pa.nc[5] = 256;
    pa.src[6] = W2_0; pa.dst[6] = w2t1; pa.kr[6] = 67;  pa.kp[6] = 96;  pa.nc[6] = 128;
    pa.src[7] = W2_1; pa.dst[7] = w2t2; pa.kr[7] = 128; pa.kp[7] = 128; pa.nc[7] = 128;
    pa.src[8] = W2_2; pa.dst[8] = w2t3; pa.kr[8] = 128; pa.kp[8] = 128; pa.nc[8] = 256;
    prep_all<<<dim3(64, 9), dim3(256), 0, stream>>>(pa);

    MlpW ww;
    ww.w[0] = w0t1; ww.w[1] = w0t2; ww.w[2] = w0t3;
    ww.w[3] = w1t1; ww.w[4] = w1t2; ww.w[5] = w1t3;
    ww.w[6] = w2t1; ww.w[7] = w2t2; ww.w[8] = w2t3;
    ww.bias[0] = b0_0; ww.bias[1] = b0_1; ww.bias[2] = b0_2;
    ww.bias[3] = b1_0; ww.bias[4] = b1_1; ww.bias[5] = b1_2;
    ww.bias[6] = b2_0; ww.bias[7] = b2_1; ww.bias[8] = b2_2;

    // dynamic LDS = scale-2 footprint: 64*104*2 + 64*136*2*2 + 256*4 = 49152 B
    mlp_all<<<dim3(3072), dim3(256), 49152, stream>>>(
        x, pos, centers, nbr0, nbr1, nbr2, nval, ww, out);
}